// Round 2
// baseline (1023.173 us; speedup 1.0000x reference)
//
#include <hip/hip_runtime.h>
#include <hip/hip_bf16.h>

// EPiC network fused implementation for MI355X (gfx950).
// Precision scheme: split-bf16 ("hi/lo") emulated-fp32 GEMMs.
//   Every MFMA operand x is stored as hi=bf16(x), lo=bf16(x-hi);
//   A*B ~= Ah*Bh + Ah*Bl + Al*Bh (3 MFMAs, fp32 accumulate).
// xl state kept in d_ws as TWO bf16 planes (hi/lo), 32MB each.
// Per EPiC block:
//   epic_global (16 WGs): pool-reduce, h_g, xg residual, fold [xg|ctx]
//     columns of l1w into per-(batch,feature) bias (fp32 throughout).
//   epic_local (2048 WGs): fused l1+l2 GEMMs via split-bf16 MFMA with LDS
//     transpose round-trip, residual+lrelu+mask epilogue, in-place xl update,
//     per-wave column sums -> partials for next block's pooling.
// Workspace requirement: ~70.1 MB.

typedef __attribute__((ext_vector_type(8))) short short8;
typedef __attribute__((ext_vector_type(4))) float f32x4;

#define B_ 16
#define N_ 8192
#define DC_ 16
#define H_ 128
#define G_ 10
#define NB_ 6
#define NEG_ 0.01f
#define TSTRIDE 136  // shorts per LDS tile row: 128 + 8 pad (272B, 16B-aligned rows)

__device__ __forceinline__ float lrelu(float x) { return x > 0.f ? x : NEG_ * x; }

__device__ __forceinline__ unsigned short f2bf(float x) {
  union { float f; unsigned u; } v; v.f = x;
  return (unsigned short)((v.u + 0x7fffu + ((v.u >> 16) & 1u)) >> 16);  // RNE
}
__device__ __forceinline__ float bf2f(unsigned short u) {
  union { unsigned u; float f; } v; v.u = ((unsigned)u) << 16; return v.f;
}
// split x into hi/lo bf16 pair
__device__ __forceinline__ void split_bf(float x, unsigned short& h, unsigned short& l) {
  h = f2bf(x);
  l = f2bf(x - bf2f(h));
}

__device__ __forceinline__ f32x4 mfma16(short8 a, short8 b, f32x4 c) {
  return __builtin_amdgcn_mfma_f32_16x16x32_bf16(a, b, c, 0, 0, 0);
}

// Shared epilogue: vectorized global store of a 32x128 hi/lo tile pair +
// per-column fp32 sums (hi+lo reconstruction).
__device__ __forceinline__ void tile_store_reduce(
    const unsigned short* th, const unsigned short* tl, int lane,
    unsigned short* gh, unsigned short* gl, float* prow) {
  {
    const int r = lane >> 1, ho = (lane & 1) * 64;
    const unsigned short* sh = th + r * TSTRIDE + ho;
    const unsigned short* sl = tl + r * TSTRIDE + ho;
    unsigned short* dh = gh + r * H_ + ho;
    unsigned short* dl = gl + r * H_ + ho;
#pragma unroll
    for (int j = 0; j < 8; ++j) {
      *(short8*)(dh + j * 8) = *(const short8*)(sh + j * 8);
      *(short8*)(dl + j * 8) = *(const short8*)(sl + j * 8);
    }
  }
  float s0 = 0.f, s1 = 0.f;
#pragma unroll 8
  for (int rr = 0; rr < 32; ++rr) {
    unsigned ph = *(const unsigned*)(th + rr * TSTRIDE + lane * 2);
    unsigned pl = *(const unsigned*)(tl + rr * TSTRIDE + lane * 2);
    s0 += bf2f((unsigned short)(ph & 0xffffu)) + bf2f((unsigned short)(pl & 0xffffu));
    s1 += bf2f((unsigned short)(ph >> 16)) + bf2f((unsigned short)(pl >> 16));
  }
  prow[lane * 2 + 0] = s0;
  prow[lane * 2 + 1] = s1;
}

// ---------------- weight prep: fp32 -> bf16 hi/lo (l1w first 128 cols, l2w) ----------------
__global__ __launch_bounds__(256) void prep_weights(
    const float* __restrict__ l1w, const float* __restrict__ l2w,
    unsigned short* __restrict__ w1h, unsigned short* __restrict__ w1l,
    unsigned short* __restrict__ w2h, unsigned short* __restrict__ w2l) {
  int idx = blockIdx.x * 256 + threadIdx.x;
  const int total = NB_ * H_ * H_;
  if (idx < total) {
    int i = idx / (H_ * H_), rem = idx % (H_ * H_);
    int n = rem / H_, k = rem % H_;
    unsigned short h, l;
    split_bf(l1w[(i * H_ + n) * 154 + k], h, l);
    w1h[idx] = h; w1l[idx] = l;
    split_bf(l2w[idx], h, l);
    w2h[idx] = h; w2l[idx] = l;
  }
}

// ---------------- projection local: xl = lrelu(x_local@plw.T + b) * mask ----------------
__global__ __launch_bounds__(256) void proj_local_kernel(
    const float* __restrict__ x_local, const float* __restrict__ mask,
    const float* __restrict__ plw, const float* __restrict__ plb,
    unsigned short* __restrict__ xlh, unsigned short* __restrict__ xll,
    float* __restrict__ partials, float* __restrict__ cntp) {
  __shared__ float wq[H_][4];
  __shared__ unsigned short th[4][32 * TSTRIDE];
  __shared__ unsigned short tl[4][32 * TSTRIDE];
  const int tid = threadIdx.x;
  if (tid < H_) {
    wq[tid][0] = plw[tid * 3 + 0];
    wq[tid][1] = plw[tid * 3 + 1];
    wq[tid][2] = plw[tid * 3 + 2];
    wq[tid][3] = plb[tid];
  }
  __syncthreads();
  const int wave = tid >> 6, lane = tid & 63;
  const int p0 = blockIdx.x * 128 + wave * 32;
  const int b = p0 >> 13;
  const int prow = lane >> 1;
  const int p = p0 + prow;
  const float x0 = x_local[p * 3 + 0], x1 = x_local[p * 3 + 1], x2 = x_local[p * 3 + 2];
  const float m = mask[p];
  unsigned short* tih = th[wave];
  unsigned short* til = tl[wave];
  const int cb = (lane & 1) * 64;
#pragma unroll
  for (int f = 0; f < 64; f += 2) {
    float4 wa = *(const float4*)wq[cb + f];
    float4 wb = *(const float4*)wq[cb + f + 1];
    float v0 = lrelu(wa.x * x0 + wa.y * x1 + wa.z * x2 + wa.w) * m;
    float v1 = lrelu(wb.x * x0 + wb.y * x1 + wb.z * x2 + wb.w) * m;
    unsigned short h0, l0, h1, l1;
    split_bf(v0, h0, l0);
    split_bf(v1, h1, l1);
    *(unsigned*)(tih + prow * TSTRIDE + cb + f) = (unsigned)h0 | ((unsigned)h1 << 16);
    *(unsigned*)(til + prow * TSTRIDE + cb + f) = (unsigned)l0 | ((unsigned)l1 << 16);
  }
  __builtin_amdgcn_wave_barrier();
  const int widx = (p0 & (N_ - 1)) >> 5;
  tile_store_reduce(tih, til, lane, xlh + (size_t)p0 * H_, xll + (size_t)p0 * H_,
                    partials + (size_t)(b * 256 + widx) * H_);
  float c = (lane & 1) ? 0.f : m;
#pragma unroll
  for (int o = 32; o; o >>= 1) c += __shfl_xor(c, o, 64);
  if (lane == 0) cntp[b * 256 + widx] = c;
}

// ---------------- projection global: 3 tiny linears -> xg (B,10); also cnt[b] ----------------
__global__ __launch_bounds__(128) void proj_global_kernel(
    const float* __restrict__ partials, const float* __restrict__ cntp,
    float* __restrict__ cnt, float* __restrict__ xg,
    const float* __restrict__ context,
    const float* __restrict__ g0w, const float* __restrict__ g0b,
    const float* __restrict__ g1w, const float* __restrict__ g1b,
    const float* __restrict__ g2w, const float* __restrict__ g2b) {
  const int b = blockIdx.x, t = threadIdx.x;
  __shared__ float pooled[272];
  __shared__ float h0[H_], h1[H_];
  __shared__ float cred[128];
  float s = 0.f;
  const float* pr = partials + (size_t)b * 256 * H_ + t;
#pragma unroll 8
  for (int w = 0; w < 256; ++w) s += pr[w * H_];
  cred[t] = cntp[b * 256 + t] + cntp[b * 256 + 128 + t];
  __syncthreads();
  for (int st = 64; st; st >>= 1) {
    if (t < st) cred[t] += cred[t + st];
    __syncthreads();
  }
  const float c = cred[0];
  if (t == 0) cnt[b] = c;
  pooled[t] = s / c;
  pooled[H_ + t] = s;
  if (t < DC_) pooled[2 * H_ + t] = context[b * DC_ + t];
  __syncthreads();
  {
    const float* wr = g0w + t * 272;
    float a = g0b[t];
#pragma unroll 8
    for (int j = 0; j < 272; ++j) a += wr[j] * pooled[j];
    h0[t] = lrelu(a);
  }
  __syncthreads();
  {
    const float* wr = g1w + t * H_;
    float a = g1b[t];
#pragma unroll 8
    for (int j = 0; j < H_; ++j) a += wr[j] * h0[j];
    h1[t] = lrelu(a);
  }
  __syncthreads();
  if (t < G_) {
    const float* wr = g2w + t * H_;
    float a = g2b[t];
#pragma unroll 8
    for (int j = 0; j < H_; ++j) a += wr[j] * h1[j];
    xg[b * G_ + t] = lrelu(a);
  }
}

// ---------------- per-block global: pool -> h_g -> xg residual -> folded gbias ----------------
__global__ __launch_bounds__(128) void epic_global_kernel(
    const float* __restrict__ partials, const float* __restrict__ cnt,
    float* __restrict__ xg, const float* __restrict__ context,
    const float* __restrict__ g1w, const float* __restrict__ g1b,
    const float* __restrict__ g2w, const float* __restrict__ g2b,
    const float* __restrict__ l1w, const float* __restrict__ l1b,
    float* __restrict__ gbias) {
  const int b = blockIdx.x, t = threadIdx.x;
  __shared__ float pooled[284];
  __shared__ float hg[H_];
  __shared__ float xgs[G_];
  float s = 0.f;
  const float* pr = partials + (size_t)b * 256 * H_ + t;
#pragma unroll 8
  for (int w = 0; w < 256; ++w) s += pr[w * H_];
  const float c = cnt[b];
  pooled[t] = s / c;        // mean
  pooled[H_ + t] = s;       // sum
  if (t < G_) pooled[2 * H_ + t] = xg[b * G_ + t];
  if (t < DC_) pooled[2 * H_ + G_ + t] = context[b * DC_ + t];
  __syncthreads();
  {
    const float* wr = g1w + t * 282;
    float a = g1b[t];
#pragma unroll 8
    for (int j = 0; j < 282; ++j) a += wr[j] * pooled[j];
    hg[t] = lrelu(a);
  }
  __syncthreads();
  if (t < G_) {
    const float* wr = g2w + t * H_;
    float a = g2b[t] + pooled[2 * H_ + t];  // residual (old xg)
#pragma unroll 8
    for (int j = 0; j < H_; ++j) a += wr[j] * hg[j];
    float v = lrelu(a);
    xgs[t] = v;
    xg[b * G_ + t] = v;
  }
  __syncthreads();
  {
    const float* wr = l1w + t * 154;
    float a = l1b[t];
#pragma unroll
    for (int j = 0; j < G_; ++j) a += wr[128 + j] * xgs[j];
#pragma unroll
    for (int j = 0; j < DC_; ++j) a += wr[138 + j] * context[b * DC_ + j];
    gbias[b * H_ + t] = a;
  }
}

// ---------------- per-block local: fused l1+l2 via split-bf16 MFMA ----------------
__global__ __launch_bounds__(128, 1) void epic_local_kernel(
    const unsigned short* __restrict__ w1h, const unsigned short* __restrict__ w1l,
    const unsigned short* __restrict__ w2h, const unsigned short* __restrict__ w2l,
    const float* __restrict__ gbias, const float* __restrict__ l2b,
    const float* __restrict__ mask,
    unsigned short* __restrict__ xlh, unsigned short* __restrict__ xll,
    float* __restrict__ partials) {
  __shared__ unsigned short xth[2][32 * TSTRIDE];
  __shared__ unsigned short xtl[2][32 * TSTRIDE];
  __shared__ unsigned short hth[2][32 * TSTRIDE];
  __shared__ unsigned short htl[2][32 * TSTRIDE];
  const int tid = threadIdx.x;
  const int wave = tid >> 6, lane = tid & 63;
  const int p0 = blockIdx.x * 64 + wave * 32;
  const int b = p0 >> 13;
  unsigned short* xh = xth[wave];
  unsigned short* xl_ = xtl[wave];
  unsigned short* hh = hth[wave];
  unsigned short* hl = htl[wave];

  // stage xl hi/lo tiles (32 rows x 256B each) into padded LDS
  {
    const unsigned short* gh = xlh + (size_t)p0 * H_;
    const unsigned short* gl = xll + (size_t)p0 * H_;
#pragma unroll
    for (int it = 0; it < 8; ++it) {
      int c16 = it * 64 + lane;
      int row = c16 >> 4, col = (c16 & 15) * 8;
      *(short8*)(xh + row * TSTRIDE + col) = *(const short8*)(gh + c16 * 8);
      *(short8*)(xl_ + row * TSTRIDE + col) = *(const short8*)(gl + c16 * 8);
    }
  }
  __builtin_amdgcn_wave_barrier();

  const int q = lane >> 4, n16 = lane & 15;

  // ---- GEMM1: h = lrelu(xl @ W1.T + gbias) ----
  f32x4 acc[2][8];
#pragma unroll
  for (int m = 0; m < 2; ++m)
#pragma unroll
    for (int n = 0; n < 8; ++n) acc[m][n] = (f32x4){0.f, 0.f, 0.f, 0.f};

#pragma unroll
  for (int ks = 0; ks < 4; ++ks) {
    const int ao = ks * 32 + q * 8;
    short8 a0h = *(const short8*)(xh + (0 * 16 + n16) * TSTRIDE + ao);
    short8 a0l = *(const short8*)(xl_ + (0 * 16 + n16) * TSTRIDE + ao);
    short8 a1h = *(const short8*)(xh + (1 * 16 + n16) * TSTRIDE + ao);
    short8 a1l = *(const short8*)(xl_ + (1 * 16 + n16) * TSTRIDE + ao);
#pragma unroll
    for (int ns = 0; ns < 8; ++ns) {
      const int wo = (ns * 16 + n16) * H_ + ao;
      short8 bh = *(const short8*)(w1h + wo);
      short8 bl = *(const short8*)(w1l + wo);
      acc[0][ns] = mfma16(a0h, bh, acc[0][ns]);
      acc[0][ns] = mfma16(a0h, bl, acc[0][ns]);
      acc[0][ns] = mfma16(a0l, bh, acc[0][ns]);
      acc[1][ns] = mfma16(a1h, bh, acc[1][ns]);
      acc[1][ns] = mfma16(a1h, bl, acc[1][ns]);
      acc[1][ns] = mfma16(a1l, bh, acc[1][ns]);
    }
  }

  float gb[8];
#pragma unroll
  for (int ns = 0; ns < 8; ++ns) gb[ns] = gbias[b * H_ + ns * 16 + n16];
#pragma unroll
  for (int m = 0; m < 2; ++m)
#pragma unroll
    for (int ns = 0; ns < 8; ++ns)
#pragma unroll
      for (int r = 0; r < 4; ++r) {
        float v = lrelu(acc[m][ns][r] + gb[ns]);
        unsigned short h, l;
        split_bf(v, h, l);
        const int o = (m * 16 + q * 4 + r) * TSTRIDE + ns * 16 + n16;
        hh[o] = h;
        hl[o] = l;
      }
  __builtin_amdgcn_wave_barrier();

  // ---- GEMM2: xl_new = lrelu(h @ W2.T + l2b + xl) * mask ----
#pragma unroll
  for (int m = 0; m < 2; ++m)
#pragma unroll
    for (int n = 0; n < 8; ++n) acc[m][n] = (f32x4){0.f, 0.f, 0.f, 0.f};

#pragma unroll
  for (int ks = 0; ks < 4; ++ks) {
    const int ao = ks * 32 + q * 8;
    short8 a0h = *(const short8*)(hh + (0 * 16 + n16) * TSTRIDE + ao);
    short8 a0l = *(const short8*)(hl + (0 * 16 + n16) * TSTRIDE + ao);
    short8 a1h = *(const short8*)(hh + (1 * 16 + n16) * TSTRIDE + ao);
    short8 a1l = *(const short8*)(hl + (1 * 16 + n16) * TSTRIDE + ao);
#pragma unroll
    for (int ns = 0; ns < 8; ++ns) {
      const int wo = (ns * 16 + n16) * H_ + ao;
      short8 bh = *(const short8*)(w2h + wo);
      short8 bl = *(const short8*)(w2l + wo);
      acc[0][ns] = mfma16(a0h, bh, acc[0][ns]);
      acc[0][ns] = mfma16(a0h, bl, acc[0][ns]);
      acc[0][ns] = mfma16(a0l, bh, acc[0][ns]);
      acc[1][ns] = mfma16(a1h, bh, acc[1][ns]);
      acc[1][ns] = mfma16(a1h, bl, acc[1][ns]);
      acc[1][ns] = mfma16(a1l, bh, acc[1][ns]);
    }
  }

  float b2[8];
#pragma unroll
  for (int ns = 0; ns < 8; ++ns) b2[ns] = l2b[ns * 16 + n16];
  float mk[2][4];
#pragma unroll
  for (int m = 0; m < 2; ++m)
#pragma unroll
    for (int r = 0; r < 4; ++r) mk[m][r] = mask[p0 + m * 16 + q * 4 + r];

#pragma unroll
  for (int m = 0; m < 2; ++m)
#pragma unroll
    for (int ns = 0; ns < 8; ++ns)
#pragma unroll
      for (int r = 0; r < 4; ++r) {
        const int row = m * 16 + q * 4 + r, col = ns * 16 + n16;
        float xv = bf2f(xh[row * TSTRIDE + col]) + bf2f(xl_[row * TSTRIDE + col]);
        float v = lrelu(acc[m][ns][r] + b2[ns] + xv) * mk[m][r];
        unsigned short h, l;
        split_bf(v, h, l);
        hh[row * TSTRIDE + col] = h;
        hl[row * TSTRIDE + col] = l;
      }
  __builtin_amdgcn_wave_barrier();

  const int widx = (p0 & (N_ - 1)) >> 5;
  tile_store_reduce(hh, hl, lane, xlh + (size_t)p0 * H_, xll + (size_t)p0 * H_,
                    partials + (size_t)(b * 256 + widx) * H_);
}

// ---------------- output head: out = (xl @ outw.T + outb) * mask ----------------
__global__ __launch_bounds__(256) void out_head_kernel(
    const unsigned short* __restrict__ xlh, const unsigned short* __restrict__ xll,
    const float* __restrict__ mask,
    const float* __restrict__ outw, const float* __restrict__ outb,
    float* __restrict__ out) {
  __shared__ float w[3][H_];
  __shared__ float bsh[4];
  const int tid = threadIdx.x;
  for (int i = tid; i < 3 * H_; i += 256) w[i / H_][i % H_] = outw[i];
  if (tid < 3) bsh[tid] = outb[tid];
  __syncthreads();
  const int p = blockIdx.x * 256 + tid;
  const unsigned short* rh = xlh + (size_t)p * H_;
  const unsigned short* rl = xll + (size_t)p * H_;
  float a0 = bsh[0], a1 = bsh[1], a2 = bsh[2];
#pragma unroll
  for (int jc = 0; jc < 16; ++jc) {
    short8 vh = *(const short8*)(rh + jc * 8);
    short8 vl = *(const short8*)(rl + jc * 8);
#pragma unroll
    for (int u = 0; u < 8; ++u) {
      float x = bf2f((unsigned short)vh[u]) + bf2f((unsigned short)vl[u]);
      int j = jc * 8 + u;
      a0 += x * w[0][j];
      a1 += x * w[1][j];
      a2 += x * w[2][j];
    }
  }
  const float m = mask[p];
  out[p * 3 + 0] = a0 * m;
  out[p * 3 + 1] = a1 * m;
  out[p * 3 + 2] = a2 * m;
}

extern "C" void kernel_launch(void* const* d_in, const int* in_sizes, int n_in,
                              void* d_out, int out_size, void* d_ws, size_t ws_size,
                              hipStream_t stream) {
  const float* x_local = (const float*)d_in[0];
  const float* context = (const float*)d_in[1];
  const float* mask = (const float*)d_in[2];
  const float* proj_lw = (const float*)d_in[3];
  const float* proj_lb = (const float*)d_in[4];
  const float* proj_g0w = (const float*)d_in[5];
  const float* proj_g0b = (const float*)d_in[6];
  const float* proj_g1w = (const float*)d_in[7];
  const float* proj_g1b = (const float*)d_in[8];
  const float* proj_g2w = (const float*)d_in[9];
  const float* proj_g2b = (const float*)d_in[10];
  const float* g1w = (const float*)d_in[11];
  const float* g1b = (const float*)d_in[12];
  const float* g2w = (const float*)d_in[13];
  const float* g2b = (const float*)d_in[14];
  const float* l1w = (const float*)d_in[15];
  const float* l1b = (const float*)d_in[16];
  const float* l2w = (const float*)d_in[17];
  const float* l2b = (const float*)d_in[18];
  const float* outw = (const float*)d_in[19];
  const float* outb = (const float*)d_in[20];
  float* out = (float*)d_out;

  char* ws = (char*)d_ws;
  unsigned short* xlh = (unsigned short*)ws;                 // 33,554,432 B
  unsigned short* xll = (unsigned short*)(ws + 33554432);    // 33,554,432 B
  float* partials = (float*)(ws + 67108864);                 //  2,097,152 B
  float* cntp = (float*)(ws + 69206016);                     //     16,384 B
  float* cnt = (float*)(ws + 69222400);                      //        256 B
  float* xg = (float*)(ws + 69222656);                       //      1,024 B
  float* gbias = (float*)(ws + 69223680);                    //      8,192 B
  unsigned short* w1h = (unsigned short*)(ws + 69231872);    //    196,608 B
  unsigned short* w1l = (unsigned short*)(ws + 69428480);    //    196,608 B
  unsigned short* w2h = (unsigned short*)(ws + 69625088);    //    196,608 B
  unsigned short* w2l = (unsigned short*)(ws + 69821696);    //    196,608 B
  // total: 70,018,304 B

  prep_weights<<<384, 256, 0, stream>>>(l1w, l2w, w1h, w1l, w2h, w2l);
  proj_local_kernel<<<1024, 256, 0, stream>>>(x_local, mask, proj_lw, proj_lb,
                                              xlh, xll, partials, cntp);
  proj_global_kernel<<<16, 128, 0, stream>>>(partials, cntp, cnt, xg, context,
                                             proj_g0w, proj_g0b, proj_g1w,
                                             proj_g1b, proj_g2w, proj_g2b);
  for (int i = 0; i < NB_; ++i) {
    epic_global_kernel<<<16, 128, 0, stream>>>(
        partials, cnt, xg, context, g1w + i * H_ * 282, g1b + i * H_,
        g2w + i * G_ * H_, g2b + i * G_, l1w + i * H_ * 154, l1b + i * H_, gbias);
    epic_local_kernel<<<2048, 128, 0, stream>>>(
        w1h + i * H_ * H_, w1l + i * H_ * H_, w2h + i * H_ * H_, w2l + i * H_ * H_,
        gbias, l2b + i * H_, mask, xlh, xll, partials);
  }
  out_head_kernel<<<512, 256, 0, stream>>>(xlh, xll, mask, outw, outb, out);
}

// Round 3
// 866.783 us; speedup vs baseline: 1.1804x; 1.1804x over previous
//
#include <hip/hip_runtime.h>
#include <hip/hip_bf16.h>

// EPiC network, round 3: fused-global-path + direct-global-A-fragment design.
// - split-bf16 (hi/lo) emulated-fp32 GEMMs: A*B ~= Ah*Bh + Al*Bh + Ah*Bl.
// - 8 dispatches: prep, proj_local, 6x epic_local (global path fused as a
//   redundant per-WG prologue; out head fused into last block).
// - partials ping-pong (pA/pB) between dispatches; xg chain via slots.
// Workspace: ~69.0 MB (<= proven 70,018,304).

typedef __attribute__((ext_vector_type(8))) short short8;
typedef __attribute__((ext_vector_type(4))) float f32x4;

#define B_ 16
#define N_ 8192
#define DC_ 16
#define H_ 128
#define G_ 10
#define NB_ 6
#define NEG_ 0.01f

__device__ __forceinline__ float lrelu(float x) { return x > 0.f ? x : NEG_ * x; }

__device__ __forceinline__ unsigned short f2bf(float x) {
  union { float f; unsigned u; } v; v.f = x;
  return (unsigned short)((v.u + 0x7fffu + ((v.u >> 16) & 1u)) >> 16);  // RNE
}
__device__ __forceinline__ float bf2f(unsigned short u) {
  union { unsigned u; float f; } v; v.u = ((unsigned)u) << 16; return v.f;
}
__device__ __forceinline__ void split_bf(float x, unsigned short& h, unsigned short& l) {
  h = f2bf(x);
  l = f2bf(x - bf2f(h));
}

__device__ __forceinline__ f32x4 mfma16(short8 a, short8 b, f32x4 c) {
  return __builtin_amdgcn_mfma_f32_16x16x32_bf16(a, b, c, 0, 0, 0);
}

// ---------------- weight prep: fp32 -> bf16 hi/lo (l1w first 128 cols, l2w) --------
__global__ __launch_bounds__(256) void prep_weights(
    const float* __restrict__ l1w, const float* __restrict__ l2w,
    unsigned short* __restrict__ w1h, unsigned short* __restrict__ w1l,
    unsigned short* __restrict__ w2h, unsigned short* __restrict__ w2l) {
  int idx = blockIdx.x * 256 + threadIdx.x;
  const int total = NB_ * H_ * H_;
  if (idx < total) {
    int i = idx / (H_ * H_), rem = idx % (H_ * H_);
    int n = rem / H_, k = rem % H_;
    unsigned short h, l;
    split_bf(l1w[(i * H_ + n) * 154 + k], h, l);
    w1h[idx] = h; w1l[idx] = l;
    split_bf(l2w[idx], h, l);
    w2h[idx] = h; w2l[idx] = l;
  }
}

// ---------------- projection local ----------------
// xl = lrelu(x_local@plw.T + b) * mask ; writes xl hi/lo, partials, cntp.
__global__ __launch_bounds__(256, 2) void proj_local_kernel(
    const float* __restrict__ xloc, const float* __restrict__ maskp,
    const float* __restrict__ plw, const float* __restrict__ plb,
    unsigned short* __restrict__ xlh, unsigned short* __restrict__ xll,
    float* __restrict__ pOut, float* __restrict__ cntp) {
  __shared__ float4 tiles4[4 * 1088];  // 4 x 17408B wave-private fp32 tiles
  __shared__ float wq[H_][4];
  __shared__ float wsum[512];
  __shared__ float cw[4];
  const int tid = threadIdx.x, bid = blockIdx.x;
  const int wv = tid >> 6, lane = tid & 63;
  const int b = bid >> 6, widx = bid & 63;
  const int p0 = bid * 128 + wv * 32;
  if (tid < H_) {
    wq[tid][0] = plw[tid * 3 + 0];
    wq[tid][1] = plw[tid * 3 + 1];
    wq[tid][2] = plw[tid * 3 + 2];
    wq[tid][3] = plb[tid];
  }
  __syncthreads();
  float* fT = (float*)(tiles4 + wv * 1088);  // stride 132 floats per row
  const int row = lane >> 1, ch = (lane & 1) * 64;
  const int p = p0 + row;
  const float x0 = xloc[p * 3 + 0], x1 = xloc[p * 3 + 1], x2 = xloc[p * 3 + 2];
  const float m = maskp[p];
#pragma unroll
  for (int g = 0; g < 8; ++g) {
    unsigned short hbuf[8], lbuf[8];
    float vbuf[8];
#pragma unroll
    for (int e = 0; e < 8; ++e) {
      const int f = ch + g * 8 + e;
      float4 w4 = *(const float4*)wq[f];
      float v = lrelu(w4.x * x0 + w4.y * x1 + w4.z * x2 + w4.w) * m;
      vbuf[e] = v;
      split_bf(v, hbuf[e], lbuf[e]);
    }
    *(short8*)(xlh + (size_t)p * H_ + ch + g * 8) = *(short8*)hbuf;
    *(short8*)(xll + (size_t)p * H_ + ch + g * 8) = *(short8*)lbuf;
    *(f32x4*)(fT + row * 132 + ch + g * 8) = (f32x4){vbuf[0], vbuf[1], vbuf[2], vbuf[3]};
    *(f32x4*)(fT + row * 132 + ch + g * 8 + 4) = (f32x4){vbuf[4], vbuf[5], vbuf[6], vbuf[7]};
  }
  // mask count (one lane per row contributes)
  float c = (lane & 1) ? 0.f : m;
#pragma unroll
  for (int o = 32; o; o >>= 1) c += __shfl_xor(c, o, 64);
  if (lane == 0) cw[wv] = c;
  __builtin_amdgcn_wave_barrier();
  // per-wave column sums
  float s0 = 0.f, s1 = 0.f;
#pragma unroll 8
  for (int r = 0; r < 32; ++r) {
    float2 t2 = *(const float2*)(fT + r * 132 + lane * 2);
    s0 += t2.x; s1 += t2.y;
  }
  wsum[wv * 128 + lane * 2 + 0] = s0;
  wsum[wv * 128 + lane * 2 + 1] = s1;
  __syncthreads();
  if (tid < 128)
    pOut[(size_t)bid * 128 + tid] =
        wsum[tid] + wsum[128 + tid] + wsum[256 + tid] + wsum[384 + tid];
  if (tid == 0) cntp[bid] = cw[0] + cw[1] + cw[2] + cw[3];
}

// ---------------- epic local: fused global-path prologue + l1/l2 GEMMs -----------
// shx float layout: [0..255] scr / wsum alias, [256..383] mean, [384..511] sum,
// [512..521] xg_cur (FIRST: ctx for g0 at 512..527), [522..537] ctx,
// [544..671] h-stage, [672..681] xg_new, [688..751] cnt scratch, [752] cnt.
template <bool FIRST, bool LAST>
__global__ __launch_bounds__(256, 2) void epic_local_kernel(
    unsigned short* __restrict__ xlh, unsigned short* __restrict__ xll,
    const float* __restrict__ pIn, float* __restrict__ pOut,
    const float* __restrict__ cntp,
    const float* __restrict__ xg_in, float* __restrict__ xg_out,
    const float* __restrict__ context,
    const float* __restrict__ g1w, const float* __restrict__ g1b,
    const float* __restrict__ g2w, const float* __restrict__ g2b,
    const float* __restrict__ l1w, const float* __restrict__ l1b,
    const float* __restrict__ l2b,
    const unsigned short* __restrict__ w1h, const unsigned short* __restrict__ w1l,
    const unsigned short* __restrict__ w2h, const unsigned short* __restrict__ w2l,
    const float* __restrict__ maskp,
    const float* __restrict__ g0w, const float* __restrict__ g0b,
    const float* __restrict__ g1pw, const float* __restrict__ g1pb,
    const float* __restrict__ g2pw, const float* __restrict__ g2pb,
    const float* __restrict__ outw, const float* __restrict__ outb,
    float* __restrict__ outp) {
  __shared__ float shx[768];
  __shared__ float gbias_s[128];
  __shared__ float4 tiles4[4 * 1088];
  const int tid = threadIdx.x, bid = blockIdx.x;
  const int b = bid >> 6, widx = bid & 63;

  // ---- prologue step 1: pooled sums + count ----
  {
    const int f = tid & 127, kh = tid >> 7;
    const float* pr = pIn + ((size_t)b * 64 + kh * 32) * 128 + f;
    float s = 0.f;
#pragma unroll 8
    for (int w = 0; w < 32; ++w) s += pr[w * 128];
    shx[tid] = s;
    if (tid < 64) shx[688 + tid] = cntp[b * 64 + tid];
  }
  __syncthreads();
  if (tid == 0) {
    float c = 0.f;
#pragma unroll
    for (int w = 0; w < 64; ++w) c += shx[688 + w];
    shx[752] = c;
  }
  __syncthreads();
  {
    if (tid < 128) {
      float s = shx[tid] + shx[tid + 128];
      shx[384 + tid] = s;
      shx[256 + tid] = s / shx[752];
    }
    if (FIRST) {
      if (tid < DC_) shx[512 + tid] = context[b * DC_ + tid];
    } else {
      if (tid < G_) shx[512 + tid] = xg_in[b * G_ + tid];
      if (tid < DC_) shx[522 + tid] = context[b * DC_ + tid];
    }
  }
  __syncthreads();

  if (FIRST) {
    // proj g0: (128, 272) over [mean,sum,ctx]
    {
      const int f = tid & 127, kh = tid >> 7;
      const float* wr = g0w + (size_t)f * 272 + kh * 136;
      const float* vp = shx + 256 + kh * 136;
      float a = 0.f;
#pragma unroll 8
      for (int j = 0; j < 34; ++j) {
        float4 w4 = *(const float4*)(wr + 4 * j);
        a += w4.x * vp[4 * j] + w4.y * vp[4 * j + 1] + w4.z * vp[4 * j + 2] + w4.w * vp[4 * j + 3];
      }
      shx[tid] = a;
    }
    __syncthreads();
    if (tid < 128) shx[544 + tid] = lrelu(shx[tid] + shx[tid + 128] + g0b[tid]);
    __syncthreads();
    // proj g1: (128,128)
    {
      const int f = tid & 127, kh = tid >> 7;
      const float* wr = g1pw + (size_t)f * 128 + kh * 64;
      const float* vp = shx + 544 + kh * 64;
      float a = 0.f;
#pragma unroll 8
      for (int j = 0; j < 16; ++j) {
        float4 w4 = *(const float4*)(wr + 4 * j);
        a += w4.x * vp[4 * j] + w4.y * vp[4 * j + 1] + w4.z * vp[4 * j + 2] + w4.w * vp[4 * j + 3];
      }
      shx[tid] = a;
    }
    __syncthreads();
    if (tid < 128) shx[544 + tid] = lrelu(shx[tid] + shx[tid + 128] + g1pb[tid]);
    __syncthreads();
    // proj g2: (10,128) -> xg_cur; restage ctx to 522
    {
      float xgp = 0.f, cv = 0.f;
      if (tid < DC_) cv = context[b * DC_ + tid];
      if (tid < G_) {
        const float* wr = g2pw + tid * 128;
        float a = g2pb[tid];
#pragma unroll 8
        for (int j = 0; j < 32; ++j) {
          float4 w4 = *(const float4*)(wr + 4 * j);
          a += w4.x * shx[544 + 4 * j] + w4.y * shx[544 + 4 * j + 1] +
               w4.z * shx[544 + 4 * j + 2] + w4.w * shx[544 + 4 * j + 3];
        }
        xgp = lrelu(a);
      }
      __syncthreads();
      if (tid < G_) shx[512 + tid] = xgp;
      if (tid < DC_) shx[522 + tid] = cv;
    }
    __syncthreads();
  }

  // ---- epic g1: (128, 282) over [mean,sum,xg,ctx] ----
  {
    const int f = tid & 127, kh = tid >> 7;
    const float* wr = g1w + (size_t)f * 282 + kh * 142;
    const float* vp = shx + 256 + kh * 142;
    const int n2 = kh ? 70 : 71;
    float a = 0.f;
#pragma unroll 8
    for (int j = 0; j < n2; ++j) {
      float2 w2 = *(const float2*)(wr + 2 * j);
      a += w2.x * vp[2 * j] + w2.y * vp[2 * j + 1];
    }
    __syncthreads();
    shx[tid] = a;
  }
  __syncthreads();
  if (tid < 128) shx[544 + tid] = lrelu(shx[tid] + shx[tid + 128] + g1b[tid]);
  __syncthreads();
  // ---- epic g2 + xg residual ----
  if (tid < G_) {
    const float* wr = g2w + tid * 128;
    float a = g2b[tid] + shx[512 + tid];
#pragma unroll 8
    for (int j = 0; j < 32; ++j) {
      float4 w4 = *(const float4*)(wr + 4 * j);
      a += w4.x * shx[544 + 4 * j] + w4.y * shx[544 + 4 * j + 1] +
           w4.z * shx[544 + 4 * j + 2] + w4.w * shx[544 + 4 * j + 3];
    }
    float v = lrelu(a);
    shx[672 + tid] = v;
    if (!LAST && widx == 0) xg_out[b * G_ + tid] = v;
  }
  __syncthreads();
  // ---- gbias: fold [xg|ctx] columns of l1w ----
  if (tid < 128) {
    const float* wr = l1w + tid * 154;
    float a = l1b[tid];
#pragma unroll
    for (int j = 0; j < G_; ++j) a += wr[128 + j] * shx[672 + j];
#pragma unroll
    for (int j = 0; j < DC_; ++j) a += wr[138 + j] * shx[522 + j];
    gbias_s[tid] = a;
  }
  __syncthreads();

  // ================= GEMM phase (per wave: 32 rows) =================
  const int wv = tid >> 6, lane = tid & 63;
  const int q = lane >> 4, n16 = lane & 15;
  const int p0 = bid * 128 + wv * 32;
  unsigned short* hh = (unsigned short*)tiles4 + wv * 8704;
  unsigned short* hl = hh + 4352;
  float* fT = (float*)hh;  // aliases hh/hl, stride 132 floats

  f32x4 acc[2][8];
#pragma unroll
  for (int m = 0; m < 2; ++m)
#pragma unroll
    for (int n = 0; n < 8; ++n) acc[m][n] = (f32x4){0.f, 0.f, 0.f, 0.f};

  // ---- GEMM1: h = lrelu(xl @ W1.T + gbias) ; A direct from global ----
  {
    short8 a0h[4], a0l[4], a1h[4], a1l[4];
#pragma unroll
    for (int ks = 0; ks < 4; ++ks) {
      const size_t r0 = (size_t)(p0 + n16) * H_ + ks * 32 + q * 8;
      const size_t r1 = (size_t)(p0 + 16 + n16) * H_ + ks * 32 + q * 8;
      a0h[ks] = *(const short8*)(xlh + r0);
      a0l[ks] = *(const short8*)(xll + r0);
      a1h[ks] = *(const short8*)(xlh + r1);
      a1l[ks] = *(const short8*)(xll + r1);
    }
#pragma unroll
    for (int ks = 0; ks < 4; ++ks)
#pragma unroll
      for (int ns = 0; ns < 8; ++ns) {
        const int wo = (ns * 16 + n16) * H_ + ks * 32 + q * 8;
        short8 bh = *(const short8*)(w1h + wo);
        short8 bl = *(const short8*)(w1l + wo);
        acc[0][ns] = mfma16(a0h[ks], bh, acc[0][ns]);
        acc[0][ns] = mfma16(a0l[ks], bh, acc[0][ns]);
        acc[0][ns] = mfma16(a0h[ks], bl, acc[0][ns]);
        acc[1][ns] = mfma16(a1h[ks], bh, acc[1][ns]);
        acc[1][ns] = mfma16(a1l[ks], bh, acc[1][ns]);
        acc[1][ns] = mfma16(a1h[ks], bl, acc[1][ns]);
      }
  }
  // ---- epilogue1: lrelu + split -> h tiles ----
  {
    float gb[8];
#pragma unroll
    for (int ns = 0; ns < 8; ++ns) gb[ns] = gbias_s[ns * 16 + n16];
#pragma unroll
    for (int m = 0; m < 2; ++m)
#pragma unroll
      for (int ns = 0; ns < 8; ++ns)
#pragma unroll
        for (int r = 0; r < 4; ++r) {
          float v = lrelu(acc[m][ns][r] + gb[ns]);
          unsigned short h, l;
          split_bf(v, h, l);
          const int o = (m * 16 + q * 4 + r) * 136 + ns * 16 + n16;
          hh[o] = h;
          hl[o] = l;
        }
  }
  __builtin_amdgcn_wave_barrier();

  // ---- GEMM2: acc2 = h @ W2.T ----
  float b2[8];
#pragma unroll
  for (int ns = 0; ns < 8; ++ns) b2[ns] = l2b[ns * 16 + n16];
#pragma unroll
  for (int m = 0; m < 2; ++m)
#pragma unroll
    for (int n = 0; n < 8; ++n) acc[m][n] = (f32x4){0.f, 0.f, 0.f, 0.f};
#pragma unroll
  for (int ks = 0; ks < 4; ++ks) {
    const int ao = ks * 32 + q * 8;
    short8 a0h = *(const short8*)(hh + (0 * 16 + n16) * 136 + ao);
    short8 a0l = *(const short8*)(hl + (0 * 16 + n16) * 136 + ao);
    short8 a1h = *(const short8*)(hh + (1 * 16 + n16) * 136 + ao);
    short8 a1l = *(const short8*)(hl + (1 * 16 + n16) * 136 + ao);
#pragma unroll
    for (int ns = 0; ns < 8; ++ns) {
      const int wo = (ns * 16 + n16) * H_ + ks * 32 + q * 8;
      short8 bh = *(const short8*)(w2h + wo);
      short8 bl = *(const short8*)(w2l + wo);
      acc[0][ns] = mfma16(a0h, bh, acc[0][ns]);
      acc[0][ns] = mfma16(a0l, bh, acc[0][ns]);
      acc[0][ns] = mfma16(a0h, bl, acc[0][ns]);
      acc[1][ns] = mfma16(a1h, bh, acc[1][ns]);
      acc[1][ns] = mfma16(a1l, bh, acc[1][ns]);
      acc[1][ns] = mfma16(a1h, bl, acc[1][ns]);
    }
  }
  __builtin_amdgcn_wave_barrier();
  // ---- epilogue2: acc2 + l2b -> fp32 tile (C layout) ----
#pragma unroll
  for (int m = 0; m < 2; ++m)
#pragma unroll
    for (int ns = 0; ns < 8; ++ns)
#pragma unroll
      for (int r = 0; r < 4; ++r)
        fT[(m * 16 + q * 4 + r) * 132 + ns * 16 + n16] = acc[m][ns][r] + b2[ns];
  __builtin_amdgcn_wave_barrier();

  // ---- store phase: row-major residual + lrelu + mask (+ out head on LAST) ----
  {
    const int row = lane >> 1, ch = (lane & 1) * 64;
    const int p = p0 + row;
    const float m = maskp[p];
    short8 oh[8], ol[8];
#pragma unroll
    for (int j = 0; j < 8; ++j) {
      oh[j] = *(const short8*)(xlh + (size_t)p * H_ + ch + j * 8);
      ol[j] = *(const short8*)(xll + (size_t)p * H_ + ch + j * 8);
    }
    float a0 = 0.f, a1 = 0.f, a2 = 0.f;
#pragma unroll
    for (int g = 0; g < 8; ++g) {
      f32x4 va = *(const f32x4*)(fT + row * 132 + ch + g * 8);
      f32x4 vb = *(const f32x4*)(fT + row * 132 + ch + g * 8 + 4);
      float v[8];
#pragma unroll
      for (int e = 0; e < 8; ++e) {
        float av = (e < 4) ? va[e] : vb[e - 4];
        float old = bf2f((unsigned short)oh[g][e]) + bf2f((unsigned short)ol[g][e]);
        v[e] = lrelu(av + old) * m;
      }
      if (LAST) {
        float4 wA0 = *(const float4*)(outw + 0 * H_ + ch + g * 8);
        float4 wB0 = *(const float4*)(outw + 0 * H_ + ch + g * 8 + 4);
        float4 wA1 = *(const float4*)(outw + 1 * H_ + ch + g * 8);
        float4 wB1 = *(const float4*)(outw + 1 * H_ + ch + g * 8 + 4);
        float4 wA2 = *(const float4*)(outw + 2 * H_ + ch + g * 8);
        float4 wB2 = *(const float4*)(outw + 2 * H_ + ch + g * 8 + 4);
        a0 += v[0]*wA0.x + v[1]*wA0.y + v[2]*wA0.z + v[3]*wA0.w + v[4]*wB0.x + v[5]*wB0.y + v[6]*wB0.z + v[7]*wB0.w;
        a1 += v[0]*wA1.x + v[1]*wA1.y + v[2]*wA1.z + v[3]*wA1.w + v[4]*wB1.x + v[5]*wB1.y + v[6]*wB1.z + v[7]*wB1.w;
        a2 += v[0]*wA2.x + v[1]*wA2.y + v[2]*wA2.z + v[3]*wA2.w + v[4]*wB2.x + v[5]*wB2.y + v[6]*wB2.z + v[7]*wB2.w;
      } else {
        unsigned short hbuf[8], lbuf[8];
#pragma unroll
        for (int e = 0; e < 8; ++e) split_bf(v[e], hbuf[e], lbuf[e]);
        *(short8*)(xlh + (size_t)p * H_ + ch + g * 8) = *(short8*)hbuf;
        *(short8*)(xll + (size_t)p * H_ + ch + g * 8) = *(short8*)lbuf;
        *(f32x4*)(fT + row * 132 + ch + g * 8) = (f32x4){v[0], v[1], v[2], v[3]};
        *(f32x4*)(fT + row * 132 + ch + g * 8 + 4) = (f32x4){v[4], v[5], v[6], v[7]};
      }
    }
    if (LAST) {
      a0 += __shfl_xor(a0, 1, 64);
      a1 += __shfl_xor(a1, 1, 64);
      a2 += __shfl_xor(a2, 1, 64);
      if ((lane & 1) == 0) {
        outp[(size_t)p * 3 + 0] = (a0 + outb[0]) * m;
        outp[(size_t)p * 3 + 1] = (a1 + outb[1]) * m;
        outp[(size_t)p * 3 + 2] = (a2 + outb[2]) * m;
      }
    }
  }
  if (!LAST) {
    __builtin_amdgcn_wave_barrier();
    float* wsum = shx;  // alias [0..511]
    float s0 = 0.f, s1 = 0.f;
#pragma unroll 8
    for (int r = 0; r < 32; ++r) {
      float2 t2 = *(const float2*)(fT + r * 132 + lane * 2);
      s0 += t2.x; s1 += t2.y;
    }
    wsum[wv * 128 + lane * 2 + 0] = s0;
    wsum[wv * 128 + lane * 2 + 1] = s1;
    __syncthreads();
    if (tid < 128)
      pOut[(size_t)bid * 128 + tid] =
          wsum[tid] + wsum[128 + tid] + wsum[256 + tid] + wsum[384 + tid];
  }
}

extern "C" void kernel_launch(void* const* d_in, const int* in_sizes, int n_in,
                              void* d_out, int out_size, void* d_ws, size_t ws_size,
                              hipStream_t stream) {
  const float* x_local = (const float*)d_in[0];
  const float* context = (const float*)d_in[1];
  const float* mask = (const float*)d_in[2];
  const float* proj_lw = (const float*)d_in[3];
  const float* proj_lb = (const float*)d_in[4];
  const float* proj_g0w = (const float*)d_in[5];
  const float* proj_g0b = (const float*)d_in[6];
  const float* proj_g1w = (const float*)d_in[7];
  const float* proj_g1b = (const float*)d_in[8];
  const float* proj_g2w = (const float*)d_in[9];
  const float* proj_g2b = (const float*)d_in[10];
  const float* g1w = (const float*)d_in[11];
  const float* g1b = (const float*)d_in[12];
  const float* g2w = (const float*)d_in[13];
  const float* g2b = (const float*)d_in[14];
  const float* l1w = (const float*)d_in[15];
  const float* l1b = (const float*)d_in[16];
  const float* l2w = (const float*)d_in[17];
  const float* l2b = (const float*)d_in[18];
  const float* outw = (const float*)d_in[19];
  const float* outb = (const float*)d_in[20];
  float* out = (float*)d_out;

  char* ws = (char*)d_ws;
  unsigned short* xlh = (unsigned short*)ws;               // 33,554,432
  unsigned short* xll = (unsigned short*)(ws + 33554432);  // 33,554,432 -> 67,108,864
  float* pA = (float*)(ws + 67108864);                     //    524,288 -> 67,633,152
  float* pB = (float*)(ws + 67633152);                     //    524,288 -> 68,157,440
  float* cntp = (float*)(ws + 68157440);                   //      4,096 -> 68,161,536
  float* xg_g = (float*)(ws + 68161536);                   //      3,840 -> 68,165,376
  unsigned short* w1h = (unsigned short*)(ws + 68165376);  //    196,608 -> 68,361,984
  unsigned short* w1l = (unsigned short*)(ws + 68361984);  //    196,608 -> 68,558,592
  unsigned short* w2h = (unsigned short*)(ws + 68558592);  //    196,608 -> 68,755,200
  unsigned short* w2l = (unsigned short*)(ws + 68755200);  //    196,608 -> 68,951,808

  prep_weights<<<384, 256, 0, stream>>>(l1w, l2w, w1h, w1l, w2h, w2l);
  proj_local_kernel<<<1024, 256, 0, stream>>>(x_local, mask, proj_lw, proj_lb,
                                              xlh, xll, pA, cntp);
  for (int i = 0; i < NB_; ++i) {
    const float* pin = (i % 2 == 0) ? pA : pB;
    float* pout = (i % 2 == 0) ? pB : pA;
    const float* xgi = xg_g + i * 160;
    float* xgo = xg_g + (i + 1) * 160;
    const float* g1w_i = g1w + (size_t)i * 128 * 282;
    const float* g1b_i = g1b + i * 128;
    const float* g2w_i = g2w + i * 10 * 128;
    const float* g2b_i = g2b + i * 10;
    const float* l1w_i = l1w + (size_t)i * 128 * 154;
    const float* l1b_i = l1b + i * 128;
    const float* l2b_i = l2b + i * 128;
    const unsigned short* w1h_i = w1h + i * 128 * 128;
    const unsigned short* w1l_i = w1l + i * 128 * 128;
    const unsigned short* w2h_i = w2h + i * 128 * 128;
    const unsigned short* w2l_i = w2l + i * 128 * 128;
    if (i == 0) {
      epic_local_kernel<true, false><<<1024, 256, 0, stream>>>(
          xlh, xll, pin, pout, cntp, xgi, xgo, context,
          g1w_i, g1b_i, g2w_i, g2b_i, l1w_i, l1b_i, l2b_i,
          w1h_i, w1l_i, w2h_i, w2l_i, mask,
          proj_g0w, proj_g0b, proj_g1w, proj_g1b, proj_g2w, proj_g2b,
          outw, outb, out);
    } else if (i == NB_ - 1) {
      epic_local_kernel<false, true><<<1024, 256, 0, stream>>>(
          xlh, xll, pin, pout, cntp, xgi, xgo, context,
          g1w_i, g1b_i, g2w_i, g2b_i, l1w_i, l1b_i, l2b_i,
          w1h_i, w1l_i, w2h_i, w2l_i, mask,
          proj_g0w, proj_g0b, proj_g1w, proj_g1b, proj_g2w, proj_g2b,
          outw, outb, out);
    } else {
      epic_local_kernel<false, false><<<1024, 256, 0, stream>>>(
          xlh, xll, pin, pout, cntp, xgi, xgo, context,
          g1w_i, g1b_i, g2w_i, g2b_i, l1w_i, l1b_i, l2b_i,
          w1h_i, w1l_i, w2h_i, w2l_i, mask,
          proj_g0w, proj_g0b, proj_g1w, proj_g1b, proj_g2w, proj_g2b,
          outw, outb, out);
    }
  }
}

// Round 5
// 788.541 us; speedup vs baseline: 1.2976x; 1.0992x over previous
//
#include <hip/hip_runtime.h>
#include <hip/hip_bf16.h>

// EPiC network, round 5: transposed-GEMM, ko-phased LDS transform.
// xl state: fp32 point-major (64 MB). Per EPiC block one 1024x256 kernel:
//  - redundant per-WG global prologue (pool -> h_g -> xg residual -> gbias)
//  - GEMM1' (h^T = W1 @ xl^T) computed 32 features per phase; lrelu+gbias;
//    round-trip through a 32x36 fp32 wave-private LDS tile into B-frag form;
//    GEMM2' (xl_new^T = W2 @ h^T) accumulates across the 4 phases.
//  - split-bf16 3-term emulation: A*B ~= Ah*Bh + Al*Bh + Ah*Bl.
//  - epilogue: residual+lrelu+mask direct on fp32 xl; shuffle partial sums;
//    LAST block fuses the output head (outw_s staging FIXED: strided loop).
// No __syncthreads in the GEMM path; no stack-array->vector casts anywhere.

typedef __attribute__((ext_vector_type(8))) short short8;
typedef __attribute__((ext_vector_type(4))) float f32x4;

#define B_ 16
#define N_ 8192
#define DC_ 16
#define H_ 128
#define G_ 10
#define NB_ 6
#define NEG_ 0.01f

__device__ __forceinline__ float lrelu(float x) { return x > 0.f ? x : NEG_ * x; }

__device__ __forceinline__ unsigned short f2bf(float x) {
  union { float f; unsigned u; } v; v.f = x;
  return (unsigned short)((v.u + 0x7fffu + ((v.u >> 16) & 1u)) >> 16);  // RNE
}
__device__ __forceinline__ float bf2f(unsigned short u) {
  union { unsigned u; float f; } v; v.u = ((unsigned)u) << 16; return v.f;
}
__device__ __forceinline__ void split_bf(float x, unsigned short& h, unsigned short& l) {
  h = f2bf(x);
  l = f2bf(x - bf2f(h));
}

__device__ __forceinline__ f32x4 mfma16(short8 a, short8 b, f32x4 c) {
  return __builtin_amdgcn_mfma_f32_16x16x32_bf16(a, b, c, 0, 0, 0);
}

// build hi/lo short8 frags from 8 fp32 values (element-insert, no stack casts)
__device__ __forceinline__ void make_frags(f32x4 v0, f32x4 v1, short8& bh, short8& bl) {
  unsigned short h, l;
#pragma unroll
  for (int j = 0; j < 4; ++j) {
    split_bf(v0[j], h, l);
    bh[j] = (short)h; bl[j] = (short)l;
  }
#pragma unroll
  for (int j = 0; j < 4; ++j) {
    split_bf(v1[j], h, l);
    bh[4 + j] = (short)h; bl[4 + j] = (short)l;
  }
}

// ---------------- weight prep: fp32 -> bf16 hi/lo (l1w first 128 cols, l2w) --------
__global__ __launch_bounds__(256) void prep_weights(
    const float* __restrict__ l1w, const float* __restrict__ l2w,
    unsigned short* __restrict__ w1h, unsigned short* __restrict__ w1l,
    unsigned short* __restrict__ w2h, unsigned short* __restrict__ w2l) {
  int idx = blockIdx.x * 256 + threadIdx.x;
  const int total = NB_ * H_ * H_;
  if (idx < total) {
    int i = idx / (H_ * H_), rem = idx % (H_ * H_);
    int n = rem / H_, k = rem % H_;
    unsigned short h, l;
    split_bf(l1w[(i * H_ + n) * 154 + k], h, l);
    w1h[idx] = h; w1l[idx] = l;
    split_bf(l2w[idx], h, l);
    w2h[idx] = h; w2l[idx] = l;
  }
}

// ---------------- projection local ----------------
__global__ __launch_bounds__(256, 2) void proj_local_kernel(
    const float* __restrict__ xloc, const float* __restrict__ maskp,
    const float* __restrict__ plw, const float* __restrict__ plb,
    float* __restrict__ xlf,
    float* __restrict__ pOut, float* __restrict__ cntp) {
  __shared__ float4 tiles4[4 * 1088];
  __shared__ float wq[H_][4];
  __shared__ float wsum[512];
  __shared__ float cw[4];
  const int tid = threadIdx.x, bid = blockIdx.x;
  const int wv = tid >> 6, lane = tid & 63;
  const int p0 = bid * 128 + wv * 32;
  if (tid < H_) {
    wq[tid][0] = plw[tid * 3 + 0];
    wq[tid][1] = plw[tid * 3 + 1];
    wq[tid][2] = plw[tid * 3 + 2];
    wq[tid][3] = plb[tid];
  }
  __syncthreads();
  float* fT = (float*)(tiles4 + wv * 1088);  // stride 132 floats per row
  const int row = lane >> 1, ch = (lane & 1) * 64;
  const int p = p0 + row;
  const float x0 = xloc[p * 3 + 0], x1 = xloc[p * 3 + 1], x2 = xloc[p * 3 + 2];
  const float m = maskp[p];
#pragma unroll
  for (int g = 0; g < 8; ++g) {
    float vbuf[8];
#pragma unroll
    for (int e = 0; e < 8; ++e) {
      const int f = ch + g * 8 + e;
      float4 w4 = *(const float4*)wq[f];
      vbuf[e] = lrelu(w4.x * x0 + w4.y * x1 + w4.z * x2 + w4.w) * m;
    }
    *(f32x4*)(xlf + (size_t)p * H_ + ch + g * 8) = (f32x4){vbuf[0], vbuf[1], vbuf[2], vbuf[3]};
    *(f32x4*)(xlf + (size_t)p * H_ + ch + g * 8 + 4) = (f32x4){vbuf[4], vbuf[5], vbuf[6], vbuf[7]};
    *(f32x4*)(fT + row * 132 + ch + g * 8) = (f32x4){vbuf[0], vbuf[1], vbuf[2], vbuf[3]};
    *(f32x4*)(fT + row * 132 + ch + g * 8 + 4) = (f32x4){vbuf[4], vbuf[5], vbuf[6], vbuf[7]};
  }
  float c = (lane & 1) ? 0.f : m;
#pragma unroll
  for (int o = 32; o; o >>= 1) c += __shfl_xor(c, o, 64);
  if (lane == 0) cw[wv] = c;
  __builtin_amdgcn_wave_barrier();
  float s0 = 0.f, s1 = 0.f;
#pragma unroll 8
  for (int r = 0; r < 32; ++r) {
    float2 t2 = *(const float2*)(fT + r * 132 + lane * 2);
    s0 += t2.x; s1 += t2.y;
  }
  wsum[wv * 128 + lane * 2 + 0] = s0;
  wsum[wv * 128 + lane * 2 + 1] = s1;
  __syncthreads();
  if (tid < 128)
    pOut[(size_t)bid * 128 + tid] =
        wsum[tid] + wsum[128 + tid] + wsum[256 + tid] + wsum[384 + tid];
  if (tid == 0) cntp[bid] = cw[0] + cw[1] + cw[2] + cw[3];
}

// ---------------- epic local ----------------
// shx: [0..255] scratch, [256..383] mean, [384..511] sum,
// [512..521] xg_cur (FIRST: ctx at 512..527), [522..537] ctx,
// [544..671] h-stage, [672..681] xg_new, [688..751] cnt scratch, [752] cnt.
template <bool FIRST, bool LAST>
__global__ __launch_bounds__(256, 2) void epic_local_kernel(
    float* __restrict__ xlf,
    const float* __restrict__ pIn, float* __restrict__ pOut,
    const float* __restrict__ cntp,
    const float* __restrict__ xg_in, float* __restrict__ xg_out,
    const float* __restrict__ context,
    const float* __restrict__ g1w, const float* __restrict__ g1b,
    const float* __restrict__ g2w, const float* __restrict__ g2b,
    const float* __restrict__ l1w, const float* __restrict__ l1b,
    const float* __restrict__ l2b,
    const unsigned short* __restrict__ w1h, const unsigned short* __restrict__ w1l,
    const unsigned short* __restrict__ w2h, const unsigned short* __restrict__ w2l,
    const float* __restrict__ maskp,
    const float* __restrict__ g0w, const float* __restrict__ g0b,
    const float* __restrict__ g1pw, const float* __restrict__ g1pb,
    const float* __restrict__ g2pw, const float* __restrict__ g2pb,
    const float* __restrict__ outw, const float* __restrict__ outb,
    float* __restrict__ outp) {
  __shared__ float shx[768];
  __shared__ float gbias_s[128];
  __shared__ float l2b_s[128];
  __shared__ float wsum[512];
  __shared__ float outw_s[392];
  __shared__ float tiles[4][1184];  // per-wave 32x36 fp32 h tile
  const int tid = threadIdx.x, bid = blockIdx.x;
  const int b = bid >> 6, widx = bid & 63;

  // ---- prologue: pooled sums + count ----
  {
    const int f = tid & 127, kh = tid >> 7;
    const float* pr = pIn + ((size_t)b * 64 + kh * 32) * 128 + f;
    float s = 0.f;
#pragma unroll 8
    for (int w = 0; w < 32; ++w) s += pr[w * 128];
    shx[tid] = s;
    if (tid < 64) shx[688 + tid] = cntp[b * 64 + tid];
  }
  if (tid < 128) l2b_s[tid] = l2b[tid];
  if (LAST) {
    for (int i = tid; i < 384; i += 256) outw_s[i] = outw[i];  // FIXED: full 384
    if (tid < 3) outw_s[384 + tid] = outb[tid];
  }
  __syncthreads();
  if (tid == 0) {
    float c = 0.f;
#pragma unroll
    for (int w = 0; w < 64; ++w) c += shx[688 + w];
    shx[752] = c;
  }
  __syncthreads();
  {
    if (tid < 128) {
      float s = shx[tid] + shx[tid + 128];
      shx[384 + tid] = s;
      shx[256 + tid] = s / shx[752];
    }
    if (FIRST) {
      if (tid < DC_) shx[512 + tid] = context[b * DC_ + tid];
    } else {
      if (tid < G_) shx[512 + tid] = xg_in[b * G_ + tid];
      if (tid < DC_) shx[522 + tid] = context[b * DC_ + tid];
    }
  }
  __syncthreads();

  if (FIRST) {
    {
      const int f = tid & 127, kh = tid >> 7;
      const float* wr = g0w + (size_t)f * 272 + kh * 136;
      const float* vp = shx + 256 + kh * 136;
      float a = 0.f;
#pragma unroll 8
      for (int j = 0; j < 34; ++j) {
        float4 w4 = *(const float4*)(wr + 4 * j);
        a += w4.x * vp[4 * j] + w4.y * vp[4 * j + 1] + w4.z * vp[4 * j + 2] + w4.w * vp[4 * j + 3];
      }
      shx[tid] = a;
    }
    __syncthreads();
    if (tid < 128) shx[544 + tid] = lrelu(shx[tid] + shx[tid + 128] + g0b[tid]);
    __syncthreads();
    {
      const int f = tid & 127, kh = tid >> 7;
      const float* wr = g1pw + (size_t)f * 128 + kh * 64;
      const float* vp = shx + 544 + kh * 64;
      float a = 0.f;
#pragma unroll 8
      for (int j = 0; j < 16; ++j) {
        float4 w4 = *(const float4*)(wr + 4 * j);
        a += w4.x * vp[4 * j] + w4.y * vp[4 * j + 1] + w4.z * vp[4 * j + 2] + w4.w * vp[4 * j + 3];
      }
      shx[tid] = a;
    }
    __syncthreads();
    if (tid < 128) shx[544 + tid] = lrelu(shx[tid] + shx[tid + 128] + g1pb[tid]);
    __syncthreads();
    {
      float xgp = 0.f, cv = 0.f;
      if (tid < DC_) cv = context[b * DC_ + tid];
      if (tid < G_) {
        const float* wr = g2pw + tid * 128;
        float a = g2pb[tid];
#pragma unroll 8
        for (int j = 0; j < 32; ++j) {
          float4 w4 = *(const float4*)(wr + 4 * j);
          a += w4.x * shx[544 + 4 * j] + w4.y * shx[544 + 4 * j + 1] +
               w4.z * shx[544 + 4 * j + 2] + w4.w * shx[544 + 4 * j + 3];
        }
        xgp = lrelu(a);
      }
      __syncthreads();
      if (tid < G_) shx[512 + tid] = xgp;
      if (tid < DC_) shx[522 + tid] = cv;
    }
    __syncthreads();
  }

  // ---- epic g1: (128, 282) over [mean,sum,xg,ctx] ----
  {
    const int f = tid & 127, kh = tid >> 7;
    const float* wr = g1w + (size_t)f * 282 + kh * 142;
    const float* vp = shx + 256 + kh * 142;
    const int n2 = kh ? 70 : 71;
    float a = 0.f;
#pragma unroll 8
    for (int j = 0; j < n2; ++j) {
      float2 w2 = *(const float2*)(wr + 2 * j);
      a += w2.x * vp[2 * j] + w2.y * vp[2 * j + 1];
    }
    __syncthreads();
    shx[tid] = a;
  }
  __syncthreads();
  if (tid < 128) shx[544 + tid] = lrelu(shx[tid] + shx[tid + 128] + g1b[tid]);
  __syncthreads();
  if (tid < G_) {
    const float* wr = g2w + tid * 128;
    float a = g2b[tid] + shx[512 + tid];
#pragma unroll 8
    for (int j = 0; j < 32; ++j) {
      float4 w4 = *(const float4*)(wr + 4 * j);
      a += w4.x * shx[544 + 4 * j] + w4.y * shx[544 + 4 * j + 1] +
           w4.z * shx[544 + 4 * j + 2] + w4.w * shx[544 + 4 * j + 3];
    }
    float v = lrelu(a);
    shx[672 + tid] = v;
    if (!LAST && widx == 0) xg_out[b * G_ + tid] = v;
  }
  __syncthreads();
  if (tid < 128) {
    const float* wr = l1w + tid * 154;
    float a = l1b[tid];
#pragma unroll
    for (int j = 0; j < G_; ++j) a += wr[128 + j] * shx[672 + j];
#pragma unroll
    for (int j = 0; j < DC_; ++j) a += wr[138 + j] * shx[522 + j];
    gbias_s[tid] = a;
  }
  __syncthreads();

  // ================= transposed GEMM phase (per wave: 32 points) =================
  const int wv = tid >> 6, lane = tid & 63;
  const int q = lane >> 4, n16 = lane & 15;
  const int p0 = bid * 128 + wv * 32;
  float* T = tiles[wv];

  // persistent xl B-frags (hi/lo), built in-register
  short8 xbh[2][4], xbl[2][4];
#pragma unroll
  for (int nt = 0; nt < 2; ++nt)
#pragma unroll
    for (int ks = 0; ks < 4; ++ks) {
      const float* xp = xlf + (size_t)(p0 + nt * 16 + n16) * H_ + ks * 32 + q * 8;
      f32x4 v0 = *(const f32x4*)xp;
      f32x4 v1 = *(const f32x4*)(xp + 4);
      short8 bh, bl;
      make_frags(v0, v1, bh, bl);
      xbh[nt][ks] = bh;
      xbl[nt][ks] = bl;
    }

  f32x4 acc2[2][8];
#pragma unroll
  for (int nt = 0; nt < 2; ++nt)
#pragma unroll
    for (int ms = 0; ms < 8; ++ms) acc2[nt][ms] = (f32x4){0.f, 0.f, 0.f, 0.f};

#pragma unroll
  for (int ko = 0; ko < 4; ++ko) {
    // ---- GEMM1' phase: h feats [ko*32, ko*32+32) ----
    f32x4 acc[2][2];
#pragma unroll
    for (int nt = 0; nt < 2; ++nt)
#pragma unroll
      for (int msl = 0; msl < 2; ++msl) acc[nt][msl] = (f32x4){0.f, 0.f, 0.f, 0.f};
#pragma unroll
    for (int ks = 0; ks < 4; ++ks)
#pragma unroll
      for (int msl = 0; msl < 2; ++msl) {
        const int wo = ((ko * 2 + msl) * 16 + n16) * H_ + ks * 32 + q * 8;
        short8 ah = *(const short8*)(w1h + wo);
        short8 al = *(const short8*)(w1l + wo);
        acc[0][msl] = mfma16(ah, xbh[0][ks], acc[0][msl]);
        acc[0][msl] = mfma16(al, xbh[0][ks], acc[0][msl]);
        acc[0][msl] = mfma16(ah, xbl[0][ks], acc[0][msl]);
        acc[1][msl] = mfma16(ah, xbh[1][ks], acc[1][msl]);
        acc[1][msl] = mfma16(al, xbh[1][ks], acc[1][msl]);
        acc[1][msl] = mfma16(ah, xbl[1][ks], acc[1][msl]);
      }
    // ---- epilogue1: lrelu+gbias -> wave tile (row=point, col=feat within 32) ----
#pragma unroll
    for (int msl = 0; msl < 2; ++msl) {
      f32x4 gb4 = *(const f32x4*)&gbias_s[(ko * 2 + msl) * 16 + q * 4];
#pragma unroll
      for (int nt = 0; nt < 2; ++nt) {
        f32x4 hv;
#pragma unroll
        for (int r = 0; r < 4; ++r) hv[r] = lrelu(acc[nt][msl][r] + gb4[r]);
        *(f32x4*)&T[(nt * 16 + n16) * 36 + msl * 16 + q * 4] = hv;
      }
    }
    __builtin_amdgcn_wave_barrier();
    // ---- read B2 frags: feats ko*32 + q*8 + j, point n16 ----
    short8 b2h[2], b2l[2];
#pragma unroll
    for (int nt = 0; nt < 2; ++nt) {
      f32x4 h0 = *(const f32x4*)&T[(nt * 16 + n16) * 36 + q * 8];
      f32x4 h1 = *(const f32x4*)&T[(nt * 16 + n16) * 36 + q * 8 + 4];
      short8 bh, bl;
      make_frags(h0, h1, bh, bl);
      b2h[nt] = bh;
      b2l[nt] = bl;
    }
    __builtin_amdgcn_wave_barrier();
    // ---- GEMM2' accumulate for k-chunk ko ----
#pragma unroll
    for (int ms = 0; ms < 8; ++ms) {
      const int wo = (ms * 16 + n16) * H_ + ko * 32 + q * 8;
      short8 ah = *(const short8*)(w2h + wo);
      short8 al = *(const short8*)(w2l + wo);
      acc2[0][ms] = mfma16(ah, b2h[0], acc2[0][ms]);
      acc2[0][ms] = mfma16(al, b2h[0], acc2[0][ms]);
      acc2[0][ms] = mfma16(ah, b2l[0], acc2[0][ms]);
      acc2[1][ms] = mfma16(ah, b2h[1], acc2[1][ms]);
      acc2[1][ms] = mfma16(al, b2h[1], acc2[1][ms]);
      acc2[1][ms] = mfma16(ah, b2l[1], acc2[1][ms]);
    }
  }

  // ---- epilogue2: residual + lrelu + mask; store fp32; partials / out head ----
  const float mk0 = maskp[p0 + n16];
  const float mk1 = maskp[p0 + 16 + n16];
  float po00 = 0.f, po01 = 0.f, po02 = 0.f;
  float po10 = 0.f, po11 = 0.f, po12 = 0.f;
#pragma unroll
  for (int ms = 0; ms < 8; ++ms) {
    f32x4 lb4 = *(const f32x4*)&l2b_s[ms * 16 + q * 4];
    f32x4 vv[2];
#pragma unroll
    for (int nt = 0; nt < 2; ++nt) {
      float* xo = xlf + (size_t)(p0 + nt * 16 + n16) * H_ + ms * 16 + q * 4;
      f32x4 old = *(const f32x4*)xo;
      const float m = nt ? mk1 : mk0;
      f32x4 v;
#pragma unroll
      for (int r = 0; r < 4; ++r) v[r] = lrelu(acc2[nt][ms][r] + lb4[r] + old[r]) * m;
      vv[nt] = v;
      if (!LAST) *(f32x4*)xo = v;
    }
    if (!LAST) {
      f32x4 sr;
#pragma unroll
      for (int r = 0; r < 4; ++r) {
        float s = vv[0][r] + vv[1][r];
        s += __shfl_xor(s, 1, 64);
        s += __shfl_xor(s, 2, 64);
        s += __shfl_xor(s, 4, 64);
        s += __shfl_xor(s, 8, 64);
        sr[r] = s;
      }
      if (n16 == 0) *(f32x4*)&wsum[wv * 128 + ms * 16 + q * 4] = sr;
    } else {
      f32x4 w0 = *(const f32x4*)&outw_s[0 * 128 + ms * 16 + q * 4];
      f32x4 w1 = *(const f32x4*)&outw_s[1 * 128 + ms * 16 + q * 4];
      f32x4 w2 = *(const f32x4*)&outw_s[2 * 128 + ms * 16 + q * 4];
#pragma unroll
      for (int r = 0; r < 4; ++r) {
        po00 += vv[0][r] * w0[r]; po01 += vv[0][r] * w1[r]; po02 += vv[0][r] * w2[r];
        po10 += vv[1][r] * w0[r]; po11 += vv[1][r] * w1[r]; po12 += vv[1][r] * w2[r];
      }
    }
  }
  if (!LAST) {
    __syncthreads();
    if (tid < 128)
      pOut[(size_t)bid * 128 + tid] =
          wsum[tid] + wsum[128 + tid] + wsum[256 + tid] + wsum[384 + tid];
  } else {
    float po[2][3] = {{po00, po01, po02}, {po10, po11, po12}};
#pragma unroll
    for (int nt = 0; nt < 2; ++nt)
#pragma unroll
      for (int o = 0; o < 3; ++o) {
        float s = po[nt][o];
        s += __shfl_xor(s, 16, 64);
        s += __shfl_xor(s, 32, 64);
        po[nt][o] = s;
      }
    if (q == 0) {
#pragma unroll
      for (int nt = 0; nt < 2; ++nt) {
        const int p = p0 + nt * 16 + n16;
        const float m = nt ? mk1 : mk0;
#pragma unroll
        for (int o = 0; o < 3; ++o)
          outp[(size_t)p * 3 + o] = (po[nt][o] + outw_s[384 + o]) * m;
      }
    }
  }
}

extern "C" void kernel_launch(void* const* d_in, const int* in_sizes, int n_in,
                              void* d_out, int out_size, void* d_ws, size_t ws_size,
                              hipStream_t stream) {
  const float* x_local = (const float*)d_in[0];
  const float* context = (const float*)d_in[1];
  const float* mask = (const float*)d_in[2];
  const float* proj_lw = (const float*)d_in[3];
  const float* proj_lb = (const float*)d_in[4];
  const float* proj_g0w = (const float*)d_in[5];
  const float* proj_g0b = (const float*)d_in[6];
  const float* proj_g1w = (const float*)d_in[7];
  const float* proj_g1b = (const float*)d_in[8];
  const float* proj_g2w = (const float*)d_in[9];
  const float* proj_g2b = (const float*)d_in[10];
  const float* g1w = (const float*)d_in[11];
  const float* g1b = (const float*)d_in[12];
  const float* g2w = (const float*)d_in[13];
  const float* g2b = (const float*)d_in[14];
  const float* l1w = (const float*)d_in[15];
  const float* l1b = (const float*)d_in[16];
  const float* l2w = (const float*)d_in[17];
  const float* l2b = (const float*)d_in[18];
  const float* outw = (const float*)d_in[19];
  const float* outb = (const float*)d_in[20];
  float* out = (float*)d_out;

  char* ws = (char*)d_ws;
  float* xlf = (float*)ws;                                 // 67,108,864
  float* pA = (float*)(ws + 67108864);                     //    524,288
  float* pB = (float*)(ws + 67633152);                     //    524,288
  float* cntp = (float*)(ws + 68157440);                   //      4,096
  float* xg_g = (float*)(ws + 68161536);                   //      3,840
  unsigned short* w1h = (unsigned short*)(ws + 68165376);  //    196,608
  unsigned short* w1l = (unsigned short*)(ws + 68361984);  //    196,608
  unsigned short* w2h = (unsigned short*)(ws + 68558592);  //    196,608
  unsigned short* w2l = (unsigned short*)(ws + 68755200);  //    196,608

  prep_weights<<<384, 256, 0, stream>>>(l1w, l2w, w1h, w1l, w2h, w2l);
  proj_local_kernel<<<1024, 256, 0, stream>>>(x_local, mask, proj_lw, proj_lb,
                                              xlf, pA, cntp);
  for (int i = 0; i < NB_; ++i) {
    const float* pin = (i % 2 == 0) ? pA : pB;
    float* pout = (i % 2 == 0) ? pB : pA;
    const float* xgi = xg_g + i * 160;
    float* xgo = xg_g + (i + 1) * 160;
    const float* g1w_i = g1w + (size_t)i * 128 * 282;
    const float* g1b_i = g1b + i * 128;
    const float* g2w_i = g2w + i * 10 * 128;
    const float* g2b_i = g2b + i * 10;
    const float* l1w_i = l1w + (size_t)i * 128 * 154;
    const float* l1b_i = l1b + i * 128;
    const float* l2b_i = l2b + i * 128;
    const unsigned short* w1h_i = w1h + i * 128 * 128;
    const unsigned short* w1l_i = w1l + i * 128 * 128;
    const unsigned short* w2h_i = w2h + i * 128 * 128;
    const unsigned short* w2l_i = w2l + i * 128 * 128;
    if (i == 0) {
      epic_local_kernel<true, false><<<1024, 256, 0, stream>>>(
          xlf, pin, pout, cntp, xgi, xgo, context,
          g1w_i, g1b_i, g2w_i, g2b_i, l1w_i, l1b_i, l2b_i,
          w1h_i, w1l_i, w2h_i, w2l_i, mask,
          proj_g0w, proj_g0b, proj_g1w, proj_g1b, proj_g2w, proj_g2b,
          outw, outb, out);
    } else if (i == NB_ - 1) {
      epic_local_kernel<false, true><<<1024, 256, 0, stream>>>(
          xlf, pin, pout, cntp, xgi, xgo, context,
          g1w_i, g1b_i, g2w_i, g2b_i, l1w_i, l1b_i, l2b_i,
          w1h_i, w1l_i, w2h_i, w2l_i, mask,
          proj_g0w, proj_g0b, proj_g1w, proj_g1b, proj_g2w, proj_g2b,
          outw, outb, out);
    } else {
      epic_local_kernel<false, false><<<1024, 256, 0, stream>>>(
          xlf, pin, pout, cntp, xgi, xgo, context,
          g1w_i, g1b_i, g2w_i, g2b_i, l1w_i, l1b_i, l2b_i,
          w1h_i, w1l_i, w2h_i, w2l_i, mask,
          proj_g0w, proj_g0b, proj_g1w, proj_g1b, proj_g2w, proj_g2b,
          outw, outb, out);
    }
  }
}